// Round 1
// baseline (809.486 us; speedup 1.0000x reference)
//
#include <hip/hip_runtime.h>
#include <cstdint>
#include <cstddef>
#include <cmath>

#define N_NODES 50000
#define N_EDGES 800000
#define D_FEAT 128
#define HIDDEN 128
#define N_CLASSES 40

// ---------------- CSR build ----------------

__global__ __launch_bounds__(256) void k_deg(const int* __restrict__ dst, int* __restrict__ deg) {
    int e = blockIdx.x * 256 + threadIdx.x;
    if (e < N_EDGES) atomicAdd(&deg[dst[e]], 1);
}

__global__ __launch_bounds__(1024) void k_scan(const int* __restrict__ deg, int* __restrict__ offsets) {
    __shared__ int sdata[1024];
    __shared__ int s_carry;
    int tid = threadIdx.x;
    if (tid == 0) s_carry = 0;
    __syncthreads();
    for (int base = 0; base < N_NODES; base += 1024) {
        int v = (base + tid < N_NODES) ? deg[base + tid] : 0;
        sdata[tid] = v;
        __syncthreads();
        for (int off = 1; off < 1024; off <<= 1) {
            int t = (tid >= off) ? sdata[tid - off] : 0;
            __syncthreads();
            sdata[tid] += t;
            __syncthreads();
        }
        int incl = sdata[tid];
        if (base + tid < N_NODES) offsets[base + tid] = s_carry + (incl - v);
        __syncthreads();
        if (tid == 1023) s_carry += sdata[1023];
        __syncthreads();
    }
}

__global__ __launch_bounds__(256) void k_scatter(const int* __restrict__ src, const int* __restrict__ dst,
                                                 const int* __restrict__ offsets, int* __restrict__ cursor,
                                                 int* __restrict__ sorted_src) {
    int e = blockIdx.x * 256 + threadIdx.x;
    if (e < N_EDGES) {
        int d = dst[e];
        int pos = offsets[d] + atomicAdd(&cursor[d], 1);
        sorted_src[pos] = src[e];
    }
}

// ---------------- mean aggregation (one wave per node) ----------------

__global__ __launch_bounds__(256) void k_agg(const float* __restrict__ feat, const int* __restrict__ offsets,
                                             const int* __restrict__ deg, const int* __restrict__ sorted_src,
                                             float* __restrict__ mean) {
    int wave = (int)((blockIdx.x * 256 + threadIdx.x) >> 6);
    int lane = threadIdx.x & 63;
    if (wave >= N_NODES) return;
    int start = offsets[wave];
    int cnt = deg[wave];
    float ax = 0.f, ay = 0.f;
    for (int i = 0; i < cnt; ++i) {
        int s = sorted_src[start + i];
        float2 v = *(const float2*)(feat + (size_t)s * D_FEAT + lane * 2);
        ax += v.x; ay += v.y;
    }
    float r = 1.0f / (float)(cnt > 0 ? cnt : 1);
    float2 o; o.x = ax * r; o.y = ay * r;
    *(float2*)(mean + (size_t)wave * D_FEAT + lane * 2) = o;
}

// ---------------- fused dual-GEMM + bias + relu (Dout = 128) ----------------
// out = relu(A @ Wl + B @ Wr + bias), A,B: [N,128], W: [128,128]

__global__ __launch_bounds__(256) void k_lin128(const float* __restrict__ A, const float* __restrict__ B,
                                                const float* __restrict__ Wl, const float* __restrict__ bias,
                                                const float* __restrict__ Wr, float* __restrict__ outp) {
    __shared__ float sA[32][128];
    __shared__ float sB[32][128];
    int t = threadIdx.x;
    int row0 = blockIdx.x * 32;
    #pragma unroll
    for (int i = 0; i < 4; ++i) {
        int idx = (i * 256 + t) * 4;   // float index within 32x128 tile
        int r = idx >> 7;
        int c = idx & 127;
        int gr = row0 + r;
        float4 va = make_float4(0.f, 0.f, 0.f, 0.f);
        float4 vb = va;
        if (gr < N_NODES) {
            va = *(const float4*)(A + (size_t)gr * 128 + c);
            vb = *(const float4*)(B + (size_t)gr * 128 + c);
        }
        *(float4*)(&sA[r][c]) = va;
        *(float4*)(&sB[r][c]) = vb;
    }
    __syncthreads();
    int c4 = (t & 31) * 4;       // 4 consecutive output cols
    int rg = (t >> 5) * 4;       // 4 consecutive rows
    float acc[4][4];
    #pragma unroll
    for (int i = 0; i < 4; ++i)
        #pragma unroll
        for (int j = 0; j < 4; ++j) acc[i][j] = 0.f;
    #pragma unroll 4
    for (int k = 0; k < 128; ++k) {
        float4 wl = *(const float4*)(Wl + k * 128 + c4);
        float4 wr = *(const float4*)(Wr + k * 128 + c4);
        #pragma unroll
        for (int i = 0; i < 4; ++i) {
            float a = sA[rg + i][k];
            float b = sB[rg + i][k];
            acc[i][0] += a * wl.x + b * wr.x;
            acc[i][1] += a * wl.y + b * wr.y;
            acc[i][2] += a * wl.z + b * wr.z;
            acc[i][3] += a * wl.w + b * wr.w;
        }
    }
    float4 bv = *(const float4*)(bias + c4);
    #pragma unroll
    for (int i = 0; i < 4; ++i) {
        int gr = row0 + rg + i;
        if (gr < N_NODES) {
            float4 o;
            o.x = fmaxf(acc[i][0] + bv.x, 0.f);
            o.y = fmaxf(acc[i][1] + bv.y, 0.f);
            o.z = fmaxf(acc[i][2] + bv.z, 0.f);
            o.w = fmaxf(acc[i][3] + bv.w, 0.f);
            *(float4*)(outp + (size_t)gr * 128 + c4) = o;
        }
    }
}

// ---------------- final layer (Dout = 40) + log_softmax, one wave per node ----------------

__global__ __launch_bounds__(256) void k_final(const float* __restrict__ A, const float* __restrict__ B,
                                               const float* __restrict__ Wl, const float* __restrict__ bias,
                                               const float* __restrict__ Wr, float* __restrict__ outp) {
    int wave = (int)((blockIdx.x * 256 + threadIdx.x) >> 6);
    int lane = threadIdx.x & 63;
    if (wave >= N_NODES) return;
    const float* arow = A + (size_t)wave * HIDDEN;
    const float* brow = B + (size_t)wave * HIDDEN;
    float acc = 0.f;
    if (lane < N_CLASSES) {
        for (int k = 0; k < HIDDEN; ++k) {
            acc += arow[k] * Wl[k * N_CLASSES + lane] + brow[k] * Wr[k * N_CLASSES + lane];
        }
        acc = fmaxf(acc + bias[lane], 0.f);
    }
    float v = (lane < N_CLASSES) ? acc : -INFINITY;
    float m = v;
    #pragma unroll
    for (int off = 32; off > 0; off >>= 1) m = fmaxf(m, __shfl_xor(m, off));
    float e = (lane < N_CLASSES) ? expf(acc - m) : 0.f;
    float s = e;
    #pragma unroll
    for (int off = 32; off > 0; off >>= 1) s += __shfl_xor(s, off);
    float lse = m + logf(s);
    if (lane < N_CLASSES) outp[(size_t)wave * N_CLASSES + lane] = acc - lse;
}

extern "C" void kernel_launch(void* const* d_in, const int* in_sizes, int n_in,
                              void* d_out, int out_size, void* d_ws, size_t ws_size,
                              hipStream_t stream) {
    const float* x   = (const float*)d_in[0];
    const int*   ei  = (const int*)d_in[1];
    const float* Wl0 = (const float*)d_in[2];
    const float* bl0 = (const float*)d_in[3];
    const float* Wr0 = (const float*)d_in[4];
    const float* Wl1 = (const float*)d_in[5];
    const float* bl1 = (const float*)d_in[6];
    const float* Wr1 = (const float*)d_in[7];
    const float* Wl2 = (const float*)d_in[8];
    const float* bl2 = (const float*)d_in[9];
    const float* Wr2 = (const float*)d_in[10];
    float* out = (float*)d_out;

    const int* src = ei;             // edge_index[0]
    const int* dst = ei + N_EDGES;   // edge_index[1]

    // workspace layout (ints padded to 50016 for alignment)
    int* offsets = (int*)d_ws;
    int* deg     = offsets + 50016;
    int* cursor  = deg + 50016;
    int* sorted  = cursor + 50016;
    float* mean  = (float*)(sorted + N_EDGES);
    float* h0    = mean + (size_t)N_NODES * HIDDEN;
    float* h1    = h0 + (size_t)N_NODES * HIDDEN;

    // zero deg + cursor (adjacent)
    hipMemsetAsync(deg, 0, 2 * 50016 * sizeof(int), stream);

    const int edgeBlocks = (N_EDGES + 255) / 256;
    k_deg<<<edgeBlocks, 256, 0, stream>>>(dst, deg);
    k_scan<<<1, 1024, 0, stream>>>(deg, offsets);
    k_scatter<<<edgeBlocks, 256, 0, stream>>>(src, dst, offsets, cursor, sorted);

    const int waveBlocks = (N_NODES * 64 + 255) / 256;
    const int linBlocks  = (N_NODES + 31) / 32;

    // layer 0
    k_agg<<<waveBlocks, 256, 0, stream>>>(x, offsets, deg, sorted, mean);
    k_lin128<<<linBlocks, 256, 0, stream>>>(mean, x, Wl0, bl0, Wr0, h0);
    // layer 1
    k_agg<<<waveBlocks, 256, 0, stream>>>(h0, offsets, deg, sorted, mean);
    k_lin128<<<linBlocks, 256, 0, stream>>>(mean, h0, Wl1, bl1, Wr1, h1);
    // layer 2 + log_softmax
    k_agg<<<waveBlocks, 256, 0, stream>>>(h1, offsets, deg, sorted, mean);
    k_final<<<waveBlocks, 256, 0, stream>>>(mean, h1, Wl2, bl2, Wr2, out);
}

// Round 2
// 658.260 us; speedup vs baseline: 1.2297x; 1.2297x over previous
//
#include <hip/hip_runtime.h>
#include <cstdint>
#include <cstddef>
#include <cmath>

#define N_NODES 50000
#define N_EDGES 800000
#define D_FEAT 128
#define HIDDEN 128
#define N_CLASSES 40

// ---------------- CSR build ----------------

__global__ __launch_bounds__(256) void k_deg(const int* __restrict__ dst, int* __restrict__ deg) {
    int e = blockIdx.x * 256 + threadIdx.x;
    if (e < N_EDGES) atomicAdd(&deg[dst[e]], 1);
}

// hierarchical exclusive scan: 49 blocks of 1024
__global__ __launch_bounds__(1024) void k_scan1(const int* __restrict__ deg, int* __restrict__ offsets,
                                                int* __restrict__ partials) {
    __shared__ int s[1024];
    int tid = threadIdx.x;
    int g = blockIdx.x * 1024 + tid;
    int v = (g < N_NODES) ? deg[g] : 0;
    s[tid] = v;
    __syncthreads();
    for (int off = 1; off < 1024; off <<= 1) {
        int t = (tid >= off) ? s[tid - off] : 0;
        __syncthreads();
        s[tid] += t;
        __syncthreads();
    }
    if (g < N_NODES) offsets[g] = s[tid] - v;   // exclusive, no carry yet
    if (tid == 1023) partials[blockIdx.x] = s[1023];
}

__global__ __launch_bounds__(64) void k_scan2(int* __restrict__ partials, int nParts) {
    int lane = threadIdx.x;
    int v = (lane < nParts) ? partials[lane] : 0;
    int incl = v;
    #pragma unroll
    for (int off = 1; off < 64; off <<= 1) {
        int t = __shfl_up(incl, off);
        if (lane >= off) incl += t;
    }
    if (lane < nParts) partials[lane] = incl - v;  // exclusive
}

__global__ __launch_bounds__(256) void k_scan3(int* __restrict__ offsets, const int* __restrict__ partials) {
    int g = blockIdx.x * 256 + threadIdx.x;
    if (g < N_NODES) offsets[g] += partials[g >> 10];
}

__global__ __launch_bounds__(256) void k_scatter(const int* __restrict__ src, const int* __restrict__ dst,
                                                 const int* __restrict__ offsets, int* __restrict__ cursor,
                                                 int* __restrict__ sorted_src) {
    int e = blockIdx.x * 256 + threadIdx.x;
    if (e < N_EDGES) {
        int d = dst[e];
        int pos = offsets[d] + atomicAdd(&cursor[d], 1);
        sorted_src[pos] = src[e];
    }
}

// ---------------- mean aggregation (one wave per node) ----------------

__global__ __launch_bounds__(256) void k_agg(const float* __restrict__ feat, const int* __restrict__ offsets,
                                             const int* __restrict__ deg, const int* __restrict__ sorted_src,
                                             float* __restrict__ mean) {
    int wave = (int)((blockIdx.x * 256 + threadIdx.x) >> 6);
    int lane = threadIdx.x & 63;
    if (wave >= N_NODES) return;
    int start = offsets[wave];
    int cnt = deg[wave];
    float ax = 0.f, ay = 0.f;
    for (int i = 0; i < cnt; ++i) {
        int s = sorted_src[start + i];
        float2 v = *(const float2*)(feat + (size_t)s * D_FEAT + lane * 2);
        ax += v.x; ay += v.y;
    }
    float r = 1.0f / (float)(cnt > 0 ? cnt : 1);
    float2 o; o.x = ax * r; o.y = ay * r;
    *(float2*)(mean + (size_t)wave * D_FEAT + lane * 2) = o;
}

// ---------------- fused dual-GEMM + bias + relu (Dout = 128), 64-row tiles ----------------
// out = relu(A @ Wl + B @ Wr + bias), A,B: [N,128], W: [128,128]

__global__ __launch_bounds__(256) void k_lin128(const float* __restrict__ A, const float* __restrict__ B,
                                                const float* __restrict__ Wl, const float* __restrict__ bias,
                                                const float* __restrict__ Wr, float* __restrict__ outp) {
    __shared__ float sA[64][128];
    __shared__ float sB[64][128];
    int t = threadIdx.x;
    int row0 = blockIdx.x * 64;
    #pragma unroll
    for (int i = 0; i < 8; ++i) {
        int idx = (i * 256 + t) * 4;   // float index within 64x128 tile
        int r = idx >> 7;
        int c = idx & 127;
        int gr = row0 + r;
        float4 va = make_float4(0.f, 0.f, 0.f, 0.f);
        float4 vb = va;
        if (gr < N_NODES) {
            va = *(const float4*)(A + (size_t)gr * 128 + c);
            vb = *(const float4*)(B + (size_t)gr * 128 + c);
        }
        *(float4*)(&sA[r][c]) = va;
        *(float4*)(&sB[r][c]) = vb;
    }
    __syncthreads();
    int c4 = (t & 31) * 4;       // 4 consecutive output cols
    int rg = (t >> 5) * 8;       // 8 consecutive rows
    float acc[8][4];
    #pragma unroll
    for (int i = 0; i < 8; ++i)
        #pragma unroll
        for (int j = 0; j < 4; ++j) acc[i][j] = 0.f;
    #pragma unroll 2
    for (int k = 0; k < 128; ++k) {
        float4 wl = *(const float4*)(Wl + k * 128 + c4);
        float4 wr = *(const float4*)(Wr + k * 128 + c4);
        #pragma unroll
        for (int i = 0; i < 8; ++i) {
            float a = sA[rg + i][k];
            float b = sB[rg + i][k];
            acc[i][0] += a * wl.x + b * wr.x;
            acc[i][1] += a * wl.y + b * wr.y;
            acc[i][2] += a * wl.z + b * wr.z;
            acc[i][3] += a * wl.w + b * wr.w;
        }
    }
    float4 bv = *(const float4*)(bias + c4);
    #pragma unroll
    for (int i = 0; i < 8; ++i) {
        int gr = row0 + rg + i;
        if (gr < N_NODES) {
            float4 o;
            o.x = fmaxf(acc[i][0] + bv.x, 0.f);
            o.y = fmaxf(acc[i][1] + bv.y, 0.f);
            o.z = fmaxf(acc[i][2] + bv.z, 0.f);
            o.w = fmaxf(acc[i][3] + bv.w, 0.f);
            *(float4*)(outp + (size_t)gr * 128 + c4) = o;
        }
    }
}

// ---------------- final layer: tiled dual-GEMM (Dout=40 padded to 64) + relu + log_softmax ----------------
// block: 256 threads, tile 64 rows x 64 cols (cols 40..63 are padding)
// thread: cg = t&15 -> cols cg*4..cg*4+3 ; rg = (t>>4)*4 -> 4 rows

__global__ __launch_bounds__(256) void k_final(const float* __restrict__ A, const float* __restrict__ B,
                                               const float* __restrict__ Wl, const float* __restrict__ bias,
                                               const float* __restrict__ Wr, float* __restrict__ outp) {
    __shared__ float sA[64][128];
    __shared__ float sB[64][128];
    int t = threadIdx.x;
    int row0 = blockIdx.x * 64;
    #pragma unroll
    for (int i = 0; i < 8; ++i) {
        int idx = (i * 256 + t) * 4;
        int r = idx >> 7;
        int c = idx & 127;
        int gr = row0 + r;
        float4 va = make_float4(0.f, 0.f, 0.f, 0.f);
        float4 vb = va;
        if (gr < N_NODES) {
            va = *(const float4*)(A + (size_t)gr * 128 + c);
            vb = *(const float4*)(B + (size_t)gr * 128 + c);
        }
        *(float4*)(&sA[r][c]) = va;
        *(float4*)(&sB[r][c]) = vb;
    }
    __syncthreads();
    int cg = t & 15;
    int c4 = cg * 4;
    int rg = (t >> 4) * 4;
    bool cvalid = (c4 < N_CLASSES);   // c4 = 0,4,...,36 valid (covers cols 0..39)
    float acc[4][4];
    #pragma unroll
    for (int i = 0; i < 4; ++i)
        #pragma unroll
        for (int j = 0; j < 4; ++j) acc[i][j] = 0.f;
    #pragma unroll 2
    for (int k = 0; k < 128; ++k) {
        float4 wl = make_float4(0.f, 0.f, 0.f, 0.f);
        float4 wr = wl;
        if (cvalid) {
            wl = *(const float4*)(Wl + k * N_CLASSES + c4);
            wr = *(const float4*)(Wr + k * N_CLASSES + c4);
        }
        #pragma unroll
        for (int i = 0; i < 4; ++i) {
            float a = sA[rg + i][k];
            float b = sB[rg + i][k];
            acc[i][0] += a * wl.x + b * wr.x;
            acc[i][1] += a * wl.y + b * wr.y;
            acc[i][2] += a * wl.z + b * wr.z;
            acc[i][3] += a * wl.w + b * wr.w;
        }
    }
    float4 bv = make_float4(0.f, 0.f, 0.f, 0.f);
    if (cvalid) bv = *(const float4*)(bias + c4);
    #pragma unroll
    for (int i = 0; i < 4; ++i) {
        float v0 = fmaxf(acc[i][0] + bv.x, 0.f);
        float v1 = fmaxf(acc[i][1] + bv.y, 0.f);
        float v2 = fmaxf(acc[i][2] + bv.z, 0.f);
        float v3 = fmaxf(acc[i][3] + bv.w, 0.f);
        // row-wise max over the 16-lane col group
        float m = cvalid ? fmaxf(fmaxf(v0, v1), fmaxf(v2, v3)) : -INFINITY;
        #pragma unroll
        for (int off = 1; off < 16; off <<= 1) m = fmaxf(m, __shfl_xor(m, off));
        float s = cvalid ? (expf(v0 - m) + expf(v1 - m) + expf(v2 - m) + expf(v3 - m)) : 0.f;
        #pragma unroll
        for (int off = 1; off < 16; off <<= 1) s += __shfl_xor(s, off);
        float lse = m + logf(s);
        int gr = row0 + rg + i;
        if (gr < N_NODES && cvalid) {
            float4 o;
            o.x = v0 - lse; o.y = v1 - lse; o.z = v2 - lse; o.w = v3 - lse;
            *(float4*)(outp + (size_t)gr * N_CLASSES + c4) = o;
        }
    }
}

extern "C" void kernel_launch(void* const* d_in, const int* in_sizes, int n_in,
                              void* d_out, int out_size, void* d_ws, size_t ws_size,
                              hipStream_t stream) {
    const float* x   = (const float*)d_in[0];
    const int*   ei  = (const int*)d_in[1];
    const float* Wl0 = (const float*)d_in[2];
    const float* bl0 = (const float*)d_in[3];
    const float* Wr0 = (const float*)d_in[4];
    const float* Wl1 = (const float*)d_in[5];
    const float* bl1 = (const float*)d_in[6];
    const float* Wr1 = (const float*)d_in[7];
    const float* Wl2 = (const float*)d_in[8];
    const float* bl2 = (const float*)d_in[9];
    const float* Wr2 = (const float*)d_in[10];
    float* out = (float*)d_out;

    const int* src = ei;             // edge_index[0]
    const int* dst = ei + N_EDGES;   // edge_index[1]

    // workspace layout
    int* offsets  = (int*)d_ws;           // 50016
    int* deg      = offsets + 50016;      // 50016
    int* cursor   = deg + 50016;          // 50016
    int* partials = cursor + 50016;       // 64
    int* sorted   = partials + 64;        // 800000
    float* mean   = (float*)(sorted + N_EDGES);
    float* h0     = mean + (size_t)N_NODES * HIDDEN;
    float* h1     = h0 + (size_t)N_NODES * HIDDEN;

    // zero deg + cursor (adjacent)
    hipMemsetAsync(deg, 0, 2 * 50016 * sizeof(int), stream);

    const int edgeBlocks = (N_EDGES + 255) / 256;
    const int scanBlocks = (N_NODES + 1023) / 1024;   // 49
    k_deg<<<edgeBlocks, 256, 0, stream>>>(dst, deg);
    k_scan1<<<scanBlocks, 1024, 0, stream>>>(deg, offsets, partials);
    k_scan2<<<1, 64, 0, stream>>>(partials, scanBlocks);
    k_scan3<<<(N_NODES + 255) / 256, 256, 0, stream>>>(offsets, partials);
    k_scatter<<<edgeBlocks, 256, 0, stream>>>(src, dst, offsets, cursor, sorted);

    const int waveBlocks = (N_NODES * 64 + 255) / 256;
    const int linBlocks  = (N_NODES + 63) / 64;

    // layer 0
    k_agg<<<waveBlocks, 256, 0, stream>>>(x, offsets, deg, sorted, mean);
    k_lin128<<<linBlocks, 256, 0, stream>>>(mean, x, Wl0, bl0, Wr0, h0);
    // layer 1
    k_agg<<<waveBlocks, 256, 0, stream>>>(h0, offsets, deg, sorted, mean);
    k_lin128<<<linBlocks, 256, 0, stream>>>(mean, h0, Wl1, bl1, Wr1, h1);
    // layer 2 + log_softmax
    k_agg<<<waveBlocks, 256, 0, stream>>>(h1, offsets, deg, sorted, mean);
    k_final<<<linBlocks, 256, 0, stream>>>(mean, h1, Wl2, bl2, Wr2, out);
}

// Round 3
// 486.390 us; speedup vs baseline: 1.6643x; 1.3534x over previous
//
#include <hip/hip_runtime.h>
#include <cstdint>
#include <cstddef>
#include <cmath>

#define N_NODES 50000
#define N_EDGES 800000
#define D_FEAT 128
#define HIDDEN 128
#define N_CLASSES 40

typedef _Float16 half8 __attribute__((ext_vector_type(8)));
typedef _Float16 half4 __attribute__((ext_vector_type(4)));
typedef _Float16 half2v __attribute__((ext_vector_type(2)));
typedef float f32x4 __attribute__((ext_vector_type(4)));

// ---------------- CSR build ----------------

__global__ __launch_bounds__(256) void k_deg(const int* __restrict__ dst, int* __restrict__ deg) {
    int e = blockIdx.x * 256 + threadIdx.x;
    if (e < N_EDGES) atomicAdd(&deg[dst[e]], 1);
}

__global__ __launch_bounds__(1024) void k_scan1(const int* __restrict__ deg, int* __restrict__ offsets,
                                                int* __restrict__ partials) {
    __shared__ int s[1024];
    int tid = threadIdx.x;
    int g = blockIdx.x * 1024 + tid;
    int v = (g < N_NODES) ? deg[g] : 0;
    s[tid] = v;
    __syncthreads();
    for (int off = 1; off < 1024; off <<= 1) {
        int t = (tid >= off) ? s[tid - off] : 0;
        __syncthreads();
        s[tid] += t;
        __syncthreads();
    }
    if (g < N_NODES) offsets[g] = s[tid] - v;
    if (tid == 1023) partials[blockIdx.x] = s[1023];
}

__global__ __launch_bounds__(64) void k_scan2(int* __restrict__ partials, int nParts) {
    int lane = threadIdx.x;
    int v = (lane < nParts) ? partials[lane] : 0;
    int incl = v;
    #pragma unroll
    for (int off = 1; off < 64; off <<= 1) {
        int t = __shfl_up(incl, off);
        if (lane >= off) incl += t;
    }
    if (lane < nParts) partials[lane] = incl - v;
}

__global__ __launch_bounds__(256) void k_scan3(int* __restrict__ offsets, const int* __restrict__ partials) {
    int g = blockIdx.x * 256 + threadIdx.x;
    if (g < N_NODES) offsets[g] += partials[g >> 10];
}

__global__ __launch_bounds__(256) void k_scatter(const int* __restrict__ src, const int* __restrict__ dst,
                                                 const int* __restrict__ offsets, int* __restrict__ cursor,
                                                 int* __restrict__ sorted_src) {
    int e = blockIdx.x * 256 + threadIdx.x;
    if (e < N_EDGES) {
        int d = dst[e];
        int pos = offsets[d] + atomicAdd(&cursor[d], 1);
        sorted_src[pos] = src[e];
    }
}

// ---------------- fp32 -> fp16 feature convert ----------------

__global__ __launch_bounds__(256) void k_cvt(const float* __restrict__ in, _Float16* __restrict__ out, int n4) {
    int i = blockIdx.x * 256 + threadIdx.x;
    if (i < n4) {
        float4 v = *(const float4*)(in + (size_t)i * 4);
        half4 o;
        o[0] = (_Float16)v.x; o[1] = (_Float16)v.y; o[2] = (_Float16)v.z; o[3] = (_Float16)v.w;
        *(half4*)(out + (size_t)i * 4) = o;
    }
}

// ---------------- weight swizzle: Wc[k][n] -> fragment-major fp16 ----------------
// element (kstep t, nfrag f, lane l, i): k = t*32 + (l>>4)*8 + i, n = f*16 + (l&15)
// stored at dst[((t*NF + f)*64 + l)*8 + i]
// W_concat[k][n] = k<128 ? Wl[k*Nout+n] : Wr[(k-128)*Nout+n]; n >= Nout -> 0

__global__ __launch_bounds__(64) void k_cvt_w(const float* __restrict__ Wl, const float* __restrict__ Wr,
                                              int Nout, int NF, _Float16* __restrict__ dst) {
    int t = blockIdx.x / NF;
    int f = blockIdx.x % NF;
    int l = threadIdx.x;
    int kb = t * 32 + (l >> 4) * 8;
    int n = f * 16 + (l & 15);
    half8 v;
    #pragma unroll
    for (int i = 0; i < 8; ++i) {
        int k = kb + i;
        float w = 0.f;
        if (n < Nout) w = (k < 128) ? Wl[k * Nout + n] : Wr[(k - 128) * Nout + n];
        v[i] = (_Float16)w;
    }
    *(half8*)(dst + ((size_t)(t * NF + f) * 64 + l) * 8) = v;
}

// ---------------- mean aggregation over fp16 features (one wave per node) ----------------

__global__ __launch_bounds__(256) void k_agg_h(const _Float16* __restrict__ feat, const int* __restrict__ offsets,
                                               const int* __restrict__ deg, const int* __restrict__ sorted_src,
                                               _Float16* __restrict__ mean) {
    int wave = (int)((blockIdx.x * 256 + threadIdx.x) >> 6);
    int lane = threadIdx.x & 63;
    if (wave >= N_NODES) return;
    int start = offsets[wave];
    int cnt = deg[wave];
    float ax = 0.f, ay = 0.f;
    for (int i = 0; i < cnt; ++i) {
        int s = sorted_src[start + i];
        half2v v = *(const half2v*)(feat + (size_t)s * 128 + lane * 2);
        ax += (float)v[0]; ay += (float)v[1];
    }
    float r = 1.0f / (float)(cnt > 0 ? cnt : 1);
    half2v o;
    o[0] = (_Float16)(ax * r);
    o[1] = (_Float16)(ay * r);
    *(half2v*)(mean + (size_t)wave * 128 + lane * 2) = o;
}

// ---------------- hidden layer MFMA GEMM: out = relu([A|B] @ Wc + bias), fp16 in/out ----------------
// per wave: 32 rows x 128 cols; K = 256 (t<4 reads A, t>=4 reads B)

__global__ __launch_bounds__(256) void k_gemm_h(const _Float16* __restrict__ A, const _Float16* __restrict__ B,
                                                const _Float16* __restrict__ Wc, const float* __restrict__ bias,
                                                _Float16* __restrict__ outp) {
    int wv = (int)((blockIdx.x * 256 + threadIdx.x) >> 6);
    int rows0 = wv * 32;
    if (rows0 >= N_NODES) return;
    int lane = threadIdx.x & 63;
    int ln = lane & 15, lg = lane >> 4;
    int m0 = rows0 + ln;
    int m1 = m0 + 16;
    int m0c = m0 < N_NODES ? m0 : N_NODES - 1;
    int m1c = m1 < N_NODES ? m1 : N_NODES - 1;
    int klane = lg * 8;
    f32x4 acc[2][8];
    #pragma unroll
    for (int i = 0; i < 2; ++i)
        #pragma unroll
        for (int f = 0; f < 8; ++f) acc[i][f] = (f32x4){0.f, 0.f, 0.f, 0.f};
    #pragma unroll
    for (int t = 0; t < 8; ++t) {
        const _Float16* P = (t < 4) ? A : B;
        int koff = (t & 3) * 32 + klane;
        half8 a0 = *(const half8*)(P + (size_t)m0c * 128 + koff);
        half8 a1 = *(const half8*)(P + (size_t)m1c * 128 + koff);
        #pragma unroll
        for (int f = 0; f < 8; ++f) {
            half8 b = *(const half8*)(Wc + ((size_t)(t * 8 + f) * 64 + lane) * 8);
            acc[0][f] = __builtin_amdgcn_mfma_f32_16x16x32_f16(a0, b, acc[0][f], 0, 0, 0);
            acc[1][f] = __builtin_amdgcn_mfma_f32_16x16x32_f16(a1, b, acc[1][f], 0, 0, 0);
        }
    }
    #pragma unroll
    for (int mf = 0; mf < 2; ++mf) {
        #pragma unroll
        for (int f = 0; f < 8; ++f) {
            int n = f * 16 + ln;
            float bv = bias[n];
            #pragma unroll
            for (int r = 0; r < 4; ++r) {
                int m = rows0 + mf * 16 + lg * 4 + r;
                if (m < N_NODES) {
                    float v = fmaxf(acc[mf][f][r] + bv, 0.f);
                    outp[(size_t)m * 128 + n] = (_Float16)v;
                }
            }
        }
    }
}

// ---------------- final layer MFMA GEMM (N=40 padded to 48) + relu + log_softmax ----------------

__global__ __launch_bounds__(256) void k_gemm_f(const _Float16* __restrict__ A, const _Float16* __restrict__ B,
                                                const _Float16* __restrict__ Wc, const float* __restrict__ bias,
                                                float* __restrict__ outp) {
    int wv = (int)((blockIdx.x * 256 + threadIdx.x) >> 6);
    int rows0 = wv * 32;
    if (rows0 >= N_NODES) return;
    int lane = threadIdx.x & 63;
    int ln = lane & 15, lg = lane >> 4;
    int m0 = rows0 + ln;
    int m1 = m0 + 16;
    int m0c = m0 < N_NODES ? m0 : N_NODES - 1;
    int m1c = m1 < N_NODES ? m1 : N_NODES - 1;
    int klane = lg * 8;
    f32x4 acc[2][3];
    #pragma unroll
    for (int i = 0; i < 2; ++i)
        #pragma unroll
        for (int f = 0; f < 3; ++f) acc[i][f] = (f32x4){0.f, 0.f, 0.f, 0.f};
    #pragma unroll
    for (int t = 0; t < 8; ++t) {
        const _Float16* P = (t < 4) ? A : B;
        int koff = (t & 3) * 32 + klane;
        half8 a0 = *(const half8*)(P + (size_t)m0c * 128 + koff);
        half8 a1 = *(const half8*)(P + (size_t)m1c * 128 + koff);
        #pragma unroll
        for (int f = 0; f < 3; ++f) {
            half8 b = *(const half8*)(Wc + ((size_t)(t * 3 + f) * 64 + lane) * 8);
            acc[0][f] = __builtin_amdgcn_mfma_f32_16x16x32_f16(a0, b, acc[0][f], 0, 0, 0);
            acc[1][f] = __builtin_amdgcn_mfma_f32_16x16x32_f16(a1, b, acc[1][f], 0, 0, 0);
        }
    }
    // biases for the 3 col groups (cols >= 40 invalid)
    float bv[3];
    #pragma unroll
    for (int f = 0; f < 3; ++f) {
        int n = f * 16 + ln;
        bv[f] = (n < N_CLASSES) ? bias[n] : 0.f;
    }
    #pragma unroll
    for (int mf = 0; mf < 2; ++mf) {
        #pragma unroll
        for (int r = 0; r < 4; ++r) {
            int m = rows0 + mf * 16 + lg * 4 + r;
            float v[3];
            float vmax = -INFINITY;
            #pragma unroll
            for (int f = 0; f < 3; ++f) {
                int n = f * 16 + ln;
                v[f] = fmaxf(acc[mf][f][r] + bv[f], 0.f);
                if (n < N_CLASSES) vmax = fmaxf(vmax, v[f]);
            }
            #pragma unroll
            for (int off = 1; off < 16; off <<= 1) vmax = fmaxf(vmax, __shfl_xor(vmax, off));
            float s = 0.f;
            #pragma unroll
            for (int f = 0; f < 3; ++f) {
                int n = f * 16 + ln;
                if (n < N_CLASSES) s += expf(v[f] - vmax);
            }
            #pragma unroll
            for (int off = 1; off < 16; off <<= 1) s += __shfl_xor(s, off);
            float lse = vmax + logf(s);
            if (m < N_NODES) {
                #pragma unroll
                for (int f = 0; f < 3; ++f) {
                    int n = f * 16 + ln;
                    if (n < N_CLASSES) outp[(size_t)m * N_CLASSES + n] = v[f] - lse;
                }
            }
        }
    }
}

extern "C" void kernel_launch(void* const* d_in, const int* in_sizes, int n_in,
                              void* d_out, int out_size, void* d_ws, size_t ws_size,
                              hipStream_t stream) {
    const float* x   = (const float*)d_in[0];
    const int*   ei  = (const int*)d_in[1];
    const float* Wl0 = (const float*)d_in[2];
    const float* bl0 = (const float*)d_in[3];
    const float* Wr0 = (const float*)d_in[4];
    const float* Wl1 = (const float*)d_in[5];
    const float* bl1 = (const float*)d_in[6];
    const float* Wr1 = (const float*)d_in[7];
    const float* Wl2 = (const float*)d_in[8];
    const float* bl2 = (const float*)d_in[9];
    const float* Wr2 = (const float*)d_in[10];
    float* out = (float*)d_out;

    const int* src = ei;
    const int* dst = ei + N_EDGES;

    // workspace layout
    int* offsets  = (int*)d_ws;           // 50016
    int* deg      = offsets + 50016;
    int* cursor   = deg + 50016;
    int* partials = cursor + 50016;       // 64
    int* sorted   = partials + 64;        // 800000
    _Float16* xh  = (_Float16*)(sorted + N_EDGES);
    _Float16* mh  = xh + (size_t)N_NODES * 128;
    _Float16* h0  = mh + (size_t)N_NODES * 128;
    _Float16* h1  = h0 + (size_t)N_NODES * 128;
    _Float16* Wc0 = h1 + (size_t)N_NODES * 128;
    _Float16* Wc1 = Wc0 + 8 * 8 * 64 * 8;
    _Float16* Wc2 = Wc1 + 8 * 8 * 64 * 8;   // 8*3*64*8

    hipMemsetAsync(deg, 0, 2 * 50016 * sizeof(int), stream);

    const int edgeBlocks = (N_EDGES + 255) / 256;
    const int scanBlocks = (N_NODES + 1023) / 1024;
    k_deg<<<edgeBlocks, 256, 0, stream>>>(dst, deg);
    k_scan1<<<scanBlocks, 1024, 0, stream>>>(deg, offsets, partials);
    k_scan2<<<1, 64, 0, stream>>>(partials, scanBlocks);
    k_scan3<<<(N_NODES + 255) / 256, 256, 0, stream>>>(offsets, partials);
    k_scatter<<<edgeBlocks, 256, 0, stream>>>(src, dst, offsets, cursor, sorted);

    // prep: fp16 features + swizzled fp16 weights
    k_cvt<<<(N_NODES * 128 / 4 + 255) / 256, 256, 0, stream>>>(x, xh, N_NODES * 128 / 4);
    k_cvt_w<<<8 * 8, 64, 0, stream>>>(Wl0, Wr0, HIDDEN, 8, Wc0);
    k_cvt_w<<<8 * 8, 64, 0, stream>>>(Wl1, Wr1, HIDDEN, 8, Wc1);
    k_cvt_w<<<8 * 3, 64, 0, stream>>>(Wl2, Wr2, N_CLASSES, 3, Wc2);

    const int waveBlocks = (N_NODES * 64 + 255) / 256;
    const int gemmBlocks = ((N_NODES + 31) / 32 + 3) / 4;   // 4 waves/block, 32 rows/wave

    // layer 0
    k_agg_h<<<waveBlocks, 256, 0, stream>>>(xh, offsets, deg, sorted, mh);
    k_gemm_h<<<gemmBlocks, 256, 0, stream>>>(mh, xh, Wc0, bl0, h0);
    // layer 1
    k_agg_h<<<waveBlocks, 256, 0, stream>>>(h0, offsets, deg, sorted, mh);
    k_gemm_h<<<gemmBlocks, 256, 0, stream>>>(mh, h0, Wc1, bl1, h1);
    // layer 2 + log_softmax
    k_agg_h<<<waveBlocks, 256, 0, stream>>>(h1, offsets, deg, sorted, mh);
    k_gemm_f<<<gemmBlocks, 256, 0, stream>>>(mh, h1, Wc2, bl2, out);
}

// Round 4
// 351.877 us; speedup vs baseline: 2.3005x; 1.3823x over previous
//
#include <hip/hip_runtime.h>
#include <cstdint>
#include <cstddef>
#include <cmath>

#define N_NODES 50000
#define N_EDGES 800000
#define D_FEAT 128
#define HIDDEN 128
#define N_CLASSES 40

typedef _Float16 half8 __attribute__((ext_vector_type(8)));
typedef _Float16 half4 __attribute__((ext_vector_type(4)));
typedef _Float16 half2v __attribute__((ext_vector_type(2)));
typedef float f32x4 __attribute__((ext_vector_type(4)));

// ---------------- CSR build ----------------

__global__ __launch_bounds__(256) void k_deg(const int* __restrict__ dst, int* __restrict__ deg) {
    int e = blockIdx.x * 256 + threadIdx.x;
    if (e < N_EDGES) atomicAdd(&deg[dst[e]], 1);
}

// shfl-based block scan: 1024 threads, 2 barriers
__global__ __launch_bounds__(1024) void k_scan1(const int* __restrict__ deg, int* __restrict__ offsets,
                                                int* __restrict__ partials) {
    __shared__ int wsums[16];
    int tid = threadIdx.x;
    int g = blockIdx.x * 1024 + tid;
    int v = (g < N_NODES) ? deg[g] : 0;
    int lane = tid & 63;
    int wid = tid >> 6;
    int incl = v;
    #pragma unroll
    for (int off = 1; off < 64; off <<= 1) {
        int t = __shfl_up(incl, off);
        if (lane >= off) incl += t;
    }
    if (lane == 63) wsums[wid] = incl;
    __syncthreads();
    if (wid == 0) {
        int wv = (lane < 16) ? wsums[lane] : 0;
        int wincl = wv;
        #pragma unroll
        for (int off = 1; off < 16; off <<= 1) {
            int t = __shfl_up(wincl, off);
            if (lane >= off) wincl += t;
        }
        if (lane < 16) wsums[lane] = wincl - wv;   // exclusive wave prefix
    }
    __syncthreads();
    if (g < N_NODES) offsets[g] = wsums[wid] + incl - v;
    if (tid == 1023) partials[blockIdx.x] = wsums[15] + incl;
}

__global__ __launch_bounds__(64) void k_scan2(int* __restrict__ partials, int nParts) {
    int lane = threadIdx.x;
    int v = (lane < nParts) ? partials[lane] : 0;
    int incl = v;
    #pragma unroll
    for (int off = 1; off < 64; off <<= 1) {
        int t = __shfl_up(incl, off);
        if (lane >= off) incl += t;
    }
    if (lane < nParts) partials[lane] = incl - v;
}

__global__ __launch_bounds__(256) void k_scan3(int* __restrict__ offsets, const int* __restrict__ partials) {
    int g = blockIdx.x * 256 + threadIdx.x;
    if (g < N_NODES) offsets[g] += partials[g >> 10];
}

__global__ __launch_bounds__(256) void k_scatter(const int* __restrict__ src, const int* __restrict__ dst,
                                                 const int* __restrict__ offsets, int* __restrict__ cursor,
                                                 int* __restrict__ sorted_src) {
    int e = blockIdx.x * 256 + threadIdx.x;
    if (e < N_EDGES) {
        int d = dst[e];
        int pos = offsets[d] + atomicAdd(&cursor[d], 1);
        sorted_src[pos] = src[e];
    }
}

// ---------------- fp32 -> fp16 feature convert ----------------

__global__ __launch_bounds__(256) void k_cvt(const float* __restrict__ in, _Float16* __restrict__ out, int n4) {
    int i = blockIdx.x * 256 + threadIdx.x;
    if (i < n4) {
        float4 v = *(const float4*)(in + (size_t)i * 4);
        half4 o;
        o[0] = (_Float16)v.x; o[1] = (_Float16)v.y; o[2] = (_Float16)v.z; o[3] = (_Float16)v.w;
        *(half4*)(out + (size_t)i * 4) = o;
    }
}

// ---------------- weight swizzle: Wc[k][n] -> fragment-major fp16 ----------------
// element (kstep t, nfrag f, lane l, i): k = t*32 + (l>>4)*8 + i, n = f*16 + (l&15)

__global__ __launch_bounds__(64) void k_cvt_w(const float* __restrict__ Wl, const float* __restrict__ Wr,
                                              int Nout, int NF, _Float16* __restrict__ dst) {
    int t = blockIdx.x / NF;
    int f = blockIdx.x % NF;
    int l = threadIdx.x;
    int kb = t * 32 + (l >> 4) * 8;
    int n = f * 16 + (l & 15);
    half8 v;
    #pragma unroll
    for (int i = 0; i < 8; ++i) {
        int k = kb + i;
        float w = 0.f;
        if (n < Nout) w = (k < 128) ? Wl[k * Nout + n] : Wr[(k - 128) * Nout + n];
        v[i] = (_Float16)w;
    }
    *(half8*)(dst + ((size_t)(t * NF + f) * 64 + l) * 8) = v;
}

// ---------------- mean aggregation: one wave per node, 4 edges in flight ----------------
// 4 groups x 16 lanes; each group gathers one edge row (16 lanes x 16B = 256B coalesced)

__global__ __launch_bounds__(256) void k_agg_h(const _Float16* __restrict__ feat, const int* __restrict__ offsets,
                                               const int* __restrict__ deg, const int* __restrict__ sorted_src,
                                               _Float16* __restrict__ mean) {
    int wave = (int)((blockIdx.x * 256 + threadIdx.x) >> 6);
    int lane = threadIdx.x & 63;
    if (wave >= N_NODES) return;
    int start = offsets[wave];
    int cnt = deg[wave];
    int grp = lane >> 4;     // 0..3: which edge in the quad
    int cl = lane & 15;      // which 8-feature chunk of the row
    float acc[8] = {0.f, 0.f, 0.f, 0.f, 0.f, 0.f, 0.f, 0.f};
    #pragma unroll 2
    for (int i = 0; i < cnt; i += 4) {
        int e = i + grp;
        if (e < cnt) {
            int s = sorted_src[start + e];
            half8 v = *(const half8*)(feat + (size_t)s * 128 + cl * 8);
            #pragma unroll
            for (int j = 0; j < 8; ++j) acc[j] += (float)v[j];
        }
    }
    // sum the 4 groups
    #pragma unroll
    for (int j = 0; j < 8; ++j) {
        acc[j] += __shfl_xor(acc[j], 16);
        acc[j] += __shfl_xor(acc[j], 32);
    }
    if (grp == 0) {
        float r = 1.0f / (float)(cnt > 0 ? cnt : 1);
        half8 o;
        #pragma unroll
        for (int j = 0; j < 8; ++j) o[j] = (_Float16)(acc[j] * r);
        *(half8*)(mean + (size_t)wave * 128 + cl * 8) = o;
    }
}

// ---------------- hidden layer MFMA GEMM: out = relu([A|B] @ Wc + bias), fp16 in/out ----------------

__global__ __launch_bounds__(256) void k_gemm_h(const _Float16* __restrict__ A, const _Float16* __restrict__ B,
                                                const _Float16* __restrict__ Wc, const float* __restrict__ bias,
                                                _Float16* __restrict__ outp) {
    int wv = (int)((blockIdx.x * 256 + threadIdx.x) >> 6);
    int rows0 = wv * 32;
    if (rows0 >= N_NODES) return;
    int lane = threadIdx.x & 63;
    int ln = lane & 15, lg = lane >> 4;
    int m0 = rows0 + ln;
    int m1 = m0 + 16;
    int m0c = m0 < N_NODES ? m0 : N_NODES - 1;
    int m1c = m1 < N_NODES ? m1 : N_NODES - 1;
    int klane = lg * 8;
    f32x4 acc[2][8];
    #pragma unroll
    for (int i = 0; i < 2; ++i)
        #pragma unroll
        for (int f = 0; f < 8; ++f) acc[i][f] = (f32x4){0.f, 0.f, 0.f, 0.f};
    #pragma unroll
    for (int t = 0; t < 8; ++t) {
        const _Float16* P = (t < 4) ? A : B;
        int koff = (t & 3) * 32 + klane;
        half8 a0 = *(const half8*)(P + (size_t)m0c * 128 + koff);
        half8 a1 = *(const half8*)(P + (size_t)m1c * 128 + koff);
        #pragma unroll
        for (int f = 0; f < 8; ++f) {
            half8 b = *(const half8*)(Wc + ((size_t)(t * 8 + f) * 64 + lane) * 8);
            acc[0][f] = __builtin_amdgcn_mfma_f32_16x16x32_f16(a0, b, acc[0][f], 0, 0, 0);
            acc[1][f] = __builtin_amdgcn_mfma_f32_16x16x32_f16(a1, b, acc[1][f], 0, 0, 0);
        }
    }
    #pragma unroll
    for (int mf = 0; mf < 2; ++mf) {
        #pragma unroll
        for (int f = 0; f < 8; ++f) {
            int n = f * 16 + ln;
            float bv = bias[n];
            #pragma unroll
            for (int r = 0; r < 4; ++r) {
                int m = rows0 + mf * 16 + lg * 4 + r;
                if (m < N_NODES) {
                    float v = fmaxf(acc[mf][f][r] + bv, 0.f);
                    outp[(size_t)m * 128 + n] = (_Float16)v;
                }
            }
        }
    }
}

// ---------------- final layer MFMA GEMM (N=40 padded to 48) + relu + log_softmax ----------------

__global__ __launch_bounds__(256) void k_gemm_f(const _Float16* __restrict__ A, const _Float16* __restrict__ B,
                                                const _Float16* __restrict__ Wc, const float* __restrict__ bias,
                                                float* __restrict__ outp) {
    int wv = (int)((blockIdx.x * 256 + threadIdx.x) >> 6);
    int rows0 = wv * 32;
    if (rows0 >= N_NODES) return;
    int lane = threadIdx.x & 63;
    int ln = lane & 15, lg = lane >> 4;
    int m0 = rows0 + ln;
    int m1 = m0 + 16;
    int m0c = m0 < N_NODES ? m0 : N_NODES - 1;
    int m1c = m1 < N_NODES ? m1 : N_NODES - 1;
    int klane = lg * 8;
    f32x4 acc[2][3];
    #pragma unroll
    for (int i = 0; i < 2; ++i)
        #pragma unroll
        for (int f = 0; f < 3; ++f) acc[i][f] = (f32x4){0.f, 0.f, 0.f, 0.f};
    #pragma unroll
    for (int t = 0; t < 8; ++t) {
        const _Float16* P = (t < 4) ? A : B;
        int koff = (t & 3) * 32 + klane;
        half8 a0 = *(const half8*)(P + (size_t)m0c * 128 + koff);
        half8 a1 = *(const half8*)(P + (size_t)m1c * 128 + koff);
        #pragma unroll
        for (int f = 0; f < 3; ++f) {
            half8 b = *(const half8*)(Wc + ((size_t)(t * 3 + f) * 64 + lane) * 8);
            acc[0][f] = __builtin_amdgcn_mfma_f32_16x16x32_f16(a0, b, acc[0][f], 0, 0, 0);
            acc[1][f] = __builtin_amdgcn_mfma_f32_16x16x32_f16(a1, b, acc[1][f], 0, 0, 0);
        }
    }
    float bv[3];
    #pragma unroll
    for (int f = 0; f < 3; ++f) {
        int n = f * 16 + ln;
        bv[f] = (n < N_CLASSES) ? bias[n] : 0.f;
    }
    #pragma unroll
    for (int mf = 0; mf < 2; ++mf) {
        #pragma unroll
        for (int r = 0; r < 4; ++r) {
            int m = rows0 + mf * 16 + lg * 4 + r;
            float v[3];
            float vmax = -INFINITY;
            #pragma unroll
            for (int f = 0; f < 3; ++f) {
                int n = f * 16 + ln;
                v[f] = fmaxf(acc[mf][f][r] + bv[f], 0.f);
                if (n < N_CLASSES) vmax = fmaxf(vmax, v[f]);
            }
            #pragma unroll
            for (int off = 1; off < 16; off <<= 1) vmax = fmaxf(vmax, __shfl_xor(vmax, off));
            float s = 0.f;
            #pragma unroll
            for (int f = 0; f < 3; ++f) {
                int n = f * 16 + ln;
                if (n < N_CLASSES) s += expf(v[f] - vmax);
            }
            #pragma unroll
            for (int off = 1; off < 16; off <<= 1) s += __shfl_xor(s, off);
            float lse = vmax + logf(s);
            if (m < N_NODES) {
                #pragma unroll
                for (int f = 0; f < 3; ++f) {
                    int n = f * 16 + ln;
                    if (n < N_CLASSES) outp[(size_t)m * N_CLASSES + n] = v[f] - lse;
                }
            }
        }
    }
}

extern "C" void kernel_launch(void* const* d_in, const int* in_sizes, int n_in,
                              void* d_out, int out_size, void* d_ws, size_t ws_size,
                              hipStream_t stream) {
    const float* x   = (const float*)d_in[0];
    const int*   ei  = (const int*)d_in[1];
    const float* Wl0 = (const float*)d_in[2];
    const float* bl0 = (const float*)d_in[3];
    const float* Wr0 = (const float*)d_in[4];
    const float* Wl1 = (const float*)d_in[5];
    const float* bl1 = (const float*)d_in[6];
    const float* Wr1 = (const float*)d_in[7];
    const float* Wl2 = (const float*)d_in[8];
    const float* bl2 = (const float*)d_in[9];
    const float* Wr2 = (const float*)d_in[10];
    float* out = (float*)d_out;

    const int* src = ei;
    const int* dst = ei + N_EDGES;

    // workspace layout
    int* offsets  = (int*)d_ws;           // 50016
    int* deg      = offsets + 50016;
    int* cursor   = deg + 50016;
    int* partials = cursor + 50016;       // 64
    int* sorted   = partials + 64;        // 800000
    _Float16* xh  = (_Float16*)(sorted + N_EDGES);
    _Float16* mh  = xh + (size_t)N_NODES * 128;
    _Float16* h0  = mh + (size_t)N_NODES * 128;
    _Float16* h1  = h0 + (size_t)N_NODES * 128;
    _Float16* Wc0 = h1 + (size_t)N_NODES * 128;
    _Float16* Wc1 = Wc0 + 8 * 8 * 64 * 8;
    _Float16* Wc2 = Wc1 + 8 * 8 * 64 * 8;

    hipMemsetAsync(deg, 0, 2 * 50016 * sizeof(int), stream);

    const int edgeBlocks = (N_EDGES + 255) / 256;
    const int scanBlocks = (N_NODES + 1023) / 1024;
    k_deg<<<edgeBlocks, 256, 0, stream>>>(dst, deg);
    k_scan1<<<scanBlocks, 1024, 0, stream>>>(deg, offsets, partials);
    k_scan2<<<1, 64, 0, stream>>>(partials, scanBlocks);
    k_scan3<<<(N_NODES + 255) / 256, 256, 0, stream>>>(offsets, partials);
    k_scatter<<<edgeBlocks, 256, 0, stream>>>(src, dst, offsets, cursor, sorted);

    // prep: fp16 features + swizzled fp16 weights
    k_cvt<<<(N_NODES * 128 / 4 + 255) / 256, 256, 0, stream>>>(x, xh, N_NODES * 128 / 4);
    k_cvt_w<<<8 * 8, 64, 0, stream>>>(Wl0, Wr0, HIDDEN, 8, Wc0);
    k_cvt_w<<<8 * 8, 64, 0, stream>>>(Wl1, Wr1, HIDDEN, 8, Wc1);
    k_cvt_w<<<8 * 3, 64, 0, stream>>>(Wl2, Wr2, N_CLASSES, 3, Wc2);

    const int waveBlocks = (N_NODES * 64 + 255) / 256;
    const int gemmBlocks = ((N_NODES + 31) / 32 + 3) / 4;

    // layer 0
    k_agg_h<<<waveBlocks, 256, 0, stream>>>(xh, offsets, deg, sorted, mh);
    k_gemm_h<<<gemmBlocks, 256, 0, stream>>>(mh, xh, Wc0, bl0, h0);
    // layer 1
    k_agg_h<<<waveBlocks, 256, 0, stream>>>(h0, offsets, deg, sorted, mh);
    k_gemm_h<<<gemmBlocks, 256, 0, stream>>>(mh, h0, Wc1, bl1, h1);
    // layer 2 + log_softmax
    k_agg_h<<<waveBlocks, 256, 0, stream>>>(h1, offsets, deg, sorted, mh);
    k_gemm_f<<<gemmBlocks, 256, 0, stream>>>(mh, h1, Wc2, bl2, out);
}

// Round 5
// 324.007 us; speedup vs baseline: 2.4984x; 1.0860x over previous
//
#include <hip/hip_runtime.h>
#include <cstdint>
#include <cstddef>
#include <cmath>

#define N_NODES 50000
#define N_EDGES 800000
#define D_FEAT 128
#define HIDDEN 128
#define N_CLASSES 40

typedef _Float16 half8 __attribute__((ext_vector_type(8)));
typedef _Float16 half4 __attribute__((ext_vector_type(4)));
typedef float f32x4 __attribute__((ext_vector_type(4)));

// ---------------- CSR build ----------------
// k_deg: count degrees AND capture each edge's rank within its dst segment.

__global__ __launch_bounds__(256) void k_deg(const int* __restrict__ dst, int* __restrict__ deg,
                                             unsigned short* __restrict__ rank) {
    int e = blockIdx.x * 256 + threadIdx.x;
    if (e < N_EDGES) {
        int r = atomicAdd(&deg[dst[e]], 1);
        rank[e] = (unsigned short)r;
    }
}

// shfl-based block scan: 1024 threads, 2 barriers
__global__ __launch_bounds__(1024) void k_scan1(const int* __restrict__ deg, int* __restrict__ offsets,
                                                int* __restrict__ partials) {
    __shared__ int wsums[16];
    int tid = threadIdx.x;
    int g = blockIdx.x * 1024 + tid;
    int v = (g < N_NODES) ? deg[g] : 0;
    int lane = tid & 63;
    int wid = tid >> 6;
    int incl = v;
    #pragma unroll
    for (int off = 1; off < 64; off <<= 1) {
        int t = __shfl_up(incl, off);
        if (lane >= off) incl += t;
    }
    if (lane == 63) wsums[wid] = incl;
    __syncthreads();
    if (wid == 0) {
        int wv = (lane < 16) ? wsums[lane] : 0;
        int wincl = wv;
        #pragma unroll
        for (int off = 1; off < 16; off <<= 1) {
            int t = __shfl_up(wincl, off);
            if (lane >= off) wincl += t;
        }
        if (lane < 16) wsums[lane] = wincl - wv;
    }
    __syncthreads();
    if (g < N_NODES) offsets[g] = wsums[wid] + incl - v;
    if (tid == 1023) partials[blockIdx.x] = wsums[15] + incl;
}

__global__ __launch_bounds__(64) void k_scan2(int* __restrict__ partials, int nParts) {
    int lane = threadIdx.x;
    int v = (lane < nParts) ? partials[lane] : 0;
    int incl = v;
    #pragma unroll
    for (int off = 1; off < 64; off <<= 1) {
        int t = __shfl_up(incl, off);
        if (lane >= off) incl += t;
    }
    if (lane < nParts) partials[lane] = incl - v;
}

__global__ __launch_bounds__(256) void k_scan3(int* __restrict__ offsets, const int* __restrict__ partials) {
    int g = blockIdx.x * 256 + threadIdx.x;
    if (g < N_NODES) offsets[g] += partials[g >> 10];
}

// no atomics: position = offsets[dst] + precomputed rank
__global__ __launch_bounds__(256) void k_scatter(const int* __restrict__ src, const int* __restrict__ dst,
                                                 const int* __restrict__ offsets,
                                                 const unsigned short* __restrict__ rank,
                                                 unsigned short* __restrict__ sorted_src) {
    int e = blockIdx.x * 256 + threadIdx.x;
    if (e < N_EDGES) {
        int d = dst[e];
        int pos = offsets[d] + (int)rank[e];
        sorted_src[pos] = (unsigned short)src[e];
    }
}

// ---------------- fp32 -> fp16 feature convert ----------------

__global__ __launch_bounds__(256) void k_cvt(const float* __restrict__ in, _Float16* __restrict__ out, int n4) {
    int i = blockIdx.x * 256 + threadIdx.x;
    if (i < n4) {
        float4 v = *(const float4*)(in + (size_t)i * 4);
        half4 o;
        o[0] = (_Float16)v.x; o[1] = (_Float16)v.y; o[2] = (_Float16)v.z; o[3] = (_Float16)v.w;
        *(half4*)(out + (size_t)i * 4) = o;
    }
}

// ---------------- weight swizzle: Wc[k][n] -> fragment-major fp16 ----------------
// element (kstep t, nfrag f, lane l, i): k = t*32 + (l>>4)*8 + i, n = f*16 + (l&15)

__global__ __launch_bounds__(64) void k_cvt_w(const float* __restrict__ Wl, const float* __restrict__ Wr,
                                              int Nout, int NF, _Float16* __restrict__ dst) {
    int t = blockIdx.x / NF;
    int f = blockIdx.x % NF;
    int l = threadIdx.x;
    int kb = t * 32 + (l >> 4) * 8;
    int n = f * 16 + (l & 15);
    half8 v;
    #pragma unroll
    for (int i = 0; i < 8; ++i) {
        int k = kb + i;
        float w = 0.f;
        if (n < Nout) w = (k < 128) ? Wl[k * Nout + n] : Wr[(k - 128) * Nout + n];
        v[i] = (_Float16)w;
    }
    *(half8*)(dst + ((size_t)(t * NF + f) * 64 + l) * 8) = v;
}

// ---------------- mean aggregation: one wave per node, 4 edge-rows in flight ----------------
// 4 groups x 16 lanes; each group gathers one edge row (16 lanes x 16B = 256B coalesced)

__global__ __launch_bounds__(256) void k_agg_h(const _Float16* __restrict__ feat, const int* __restrict__ offsets,
                                               const int* __restrict__ deg,
                                               const unsigned short* __restrict__ sorted_src,
                                               _Float16* __restrict__ mean) {
    int wave = (int)((blockIdx.x * 256 + threadIdx.x) >> 6);
    int lane = threadIdx.x & 63;
    if (wave >= N_NODES) return;
    int start = offsets[wave];
    int cnt = deg[wave];
    int grp = lane >> 4;     // 0..3: which edge in the quad
    int cl = lane & 15;      // which 8-feature chunk of the row
    float acc[8] = {0.f, 0.f, 0.f, 0.f, 0.f, 0.f, 0.f, 0.f};
    #pragma unroll 4
    for (int i = 0; i < cnt; i += 4) {
        int e = i + grp;
        if (e < cnt) {
            int s = (int)sorted_src[start + e];
            half8 v = *(const half8*)(feat + (size_t)s * 128 + cl * 8);
            #pragma unroll
            for (int j = 0; j < 8; ++j) acc[j] += (float)v[j];
        }
    }
    #pragma unroll
    for (int j = 0; j < 8; ++j) {
        acc[j] += __shfl_xor(acc[j], 16);
        acc[j] += __shfl_xor(acc[j], 32);
    }
    if (grp == 0) {
        float r = 1.0f / (float)(cnt > 0 ? cnt : 1);
        half8 o;
        #pragma unroll
        for (int j = 0; j < 8; ++j) o[j] = (_Float16)(acc[j] * r);
        *(half8*)(mean + (size_t)wave * 128 + cl * 8) = o;
    }
}

// ---------------- hidden layer MFMA GEMM: out = relu([A|B] @ Wc + bias), fp16 in/out ----------------

__global__ __launch_bounds__(256) void k_gemm_h(const _Float16* __restrict__ A, const _Float16* __restrict__ B,
                                                const _Float16* __restrict__ Wc, const float* __restrict__ bias,
                                                _Float16* __restrict__ outp) {
    int wv = (int)((blockIdx.x * 256 + threadIdx.x) >> 6);
    int rows0 = wv * 32;
    if (rows0 >= N_NODES) return;
    int lane = threadIdx.x & 63;
    int ln = lane & 15, lg = lane >> 4;
    int m0 = rows0 + ln;
    int m1 = m0 + 16;
    int m0c = m0 < N_NODES ? m0 : N_NODES - 1;
    int m1c = m1 < N_NODES ? m1 : N_NODES - 1;
    int klane = lg * 8;
    f32x4 acc[2][8];
    #pragma unroll
    for (int i = 0; i < 2; ++i)
        #pragma unroll
        for (int f = 0; f < 8; ++f) acc[i][f] = (f32x4){0.f, 0.f, 0.f, 0.f};
    #pragma unroll
    for (int t = 0; t < 8; ++t) {
        const _Float16* P = (t < 4) ? A : B;
        int koff = (t & 3) * 32 + klane;
        half8 a0 = *(const half8*)(P + (size_t)m0c * 128 + koff);
        half8 a1 = *(const half8*)(P + (size_t)m1c * 128 + koff);
        #pragma unroll
        for (int f = 0; f < 8; ++f) {
            half8 b = *(const half8*)(Wc + ((size_t)(t * 8 + f) * 64 + lane) * 8);
            acc[0][f] = __builtin_amdgcn_mfma_f32_16x16x32_f16(a0, b, acc[0][f], 0, 0, 0);
            acc[1][f] = __builtin_amdgcn_mfma_f32_16x16x32_f16(a1, b, acc[1][f], 0, 0, 0);
        }
    }
    #pragma unroll
    for (int mf = 0; mf < 2; ++mf) {
        #pragma unroll
        for (int f = 0; f < 8; ++f) {
            int n = f * 16 + ln;
            float bv = bias[n];
            #pragma unroll
            for (int r = 0; r < 4; ++r) {
                int m = rows0 + mf * 16 + lg * 4 + r;
                if (m < N_NODES) {
                    float v = fmaxf(acc[mf][f][r] + bv, 0.f);
                    outp[(size_t)m * 128 + n] = (_Float16)v;
                }
            }
        }
    }
}

// ---------------- final layer MFMA GEMM (N=40 padded to 48) + relu + log_softmax ----------------

__global__ __launch_bounds__(256) void k_gemm_f(const _Float16* __restrict__ A, const _Float16* __restrict__ B,
                                                const _Float16* __restrict__ Wc, const float* __restrict__ bias,
                                                float* __restrict__ outp) {
    int wv = (int)((blockIdx.x * 256 + threadIdx.x) >> 6);
    int rows0 = wv * 32;
    if (rows0 >= N_NODES) return;
    int lane = threadIdx.x & 63;
    int ln = lane & 15, lg = lane >> 4;
    int m0 = rows0 + ln;
    int m1 = m0 + 16;
    int m0c = m0 < N_NODES ? m0 : N_NODES - 1;
    int m1c = m1 < N_NODES ? m1 : N_NODES - 1;
    int klane = lg * 8;
    f32x4 acc[2][3];
    #pragma unroll
    for (int i = 0; i < 2; ++i)
        #pragma unroll
        for (int f = 0; f < 3; ++f) acc[i][f] = (f32x4){0.f, 0.f, 0.f, 0.f};
    #pragma unroll
    for (int t = 0; t < 8; ++t) {
        const _Float16* P = (t < 4) ? A : B;
        int koff = (t & 3) * 32 + klane;
        half8 a0 = *(const half8*)(P + (size_t)m0c * 128 + koff);
        half8 a1 = *(const half8*)(P + (size_t)m1c * 128 + koff);
        #pragma unroll
        for (int f = 0; f < 3; ++f) {
            half8 b = *(const half8*)(Wc + ((size_t)(t * 3 + f) * 64 + lane) * 8);
            acc[0][f] = __builtin_amdgcn_mfma_f32_16x16x32_f16(a0, b, acc[0][f], 0, 0, 0);
            acc[1][f] = __builtin_amdgcn_mfma_f32_16x16x32_f16(a1, b, acc[1][f], 0, 0, 0);
        }
    }
    float bv[3];
    #pragma unroll
    for (int f = 0; f < 3; ++f) {
        int n = f * 16 + ln;
        bv[f] = (n < N_CLASSES) ? bias[n] : 0.f;
    }
    #pragma unroll
    for (int mf = 0; mf < 2; ++mf) {
        #pragma unroll
        for (int r = 0; r < 4; ++r) {
            int m = rows0 + mf * 16 + lg * 4 + r;
            float v[3];
            float vmax = -INFINITY;
            #pragma unroll
            for (int f = 0; f < 3; ++f) {
                int n = f * 16 + ln;
                v[f] = fmaxf(acc[mf][f][r] + bv[f], 0.f);
                if (n < N_CLASSES) vmax = fmaxf(vmax, v[f]);
            }
            #pragma unroll
            for (int off = 1; off < 16; off <<= 1) vmax = fmaxf(vmax, __shfl_xor(vmax, off));
            float s = 0.f;
            #pragma unroll
            for (int f = 0; f < 3; ++f) {
                int n = f * 16 + ln;
                if (n < N_CLASSES) s += expf(v[f] - vmax);
            }
            #pragma unroll
            for (int off = 1; off < 16; off <<= 1) s += __shfl_xor(s, off);
            float lse = vmax + logf(s);
            if (m < N_NODES) {
                #pragma unroll
                for (int f = 0; f < 3; ++f) {
                    int n = f * 16 + ln;
                    if (n < N_CLASSES) outp[(size_t)m * N_CLASSES + n] = v[f] - lse;
                }
            }
        }
    }
}

extern "C" void kernel_launch(void* const* d_in, const int* in_sizes, int n_in,
                              void* d_out, int out_size, void* d_ws, size_t ws_size,
                              hipStream_t stream) {
    const float* x   = (const float*)d_in[0];
    const int*   ei  = (const int*)d_in[1];
    const float* Wl0 = (const float*)d_in[2];
    const float* bl0 = (const float*)d_in[3];
    const float* Wr0 = (const float*)d_in[4];
    const float* Wl1 = (const float*)d_in[5];
    const float* bl1 = (const float*)d_in[6];
    const float* Wr1 = (const float*)d_in[7];
    const float* Wl2 = (const float*)d_in[8];
    const float* bl2 = (const float*)d_in[9];
    const float* Wr2 = (const float*)d_in[10];
    float* out = (float*)d_out;

    const int* src = ei;
    const int* dst = ei + N_EDGES;

    // workspace layout
    int* offsets  = (int*)d_ws;                         // 50016 ints
    int* deg      = offsets + 50016;                    // 50016 ints
    int* partials = deg + 50016;                        // 64 ints
    unsigned short* rank   = (unsigned short*)(partials + 64);   // 800k u16
    unsigned short* sorted = rank + N_EDGES;                     // 800k u16
    _Float16* xh  = (_Float16*)(sorted + N_EDGES);
    _Float16* mh  = xh + (size_t)N_NODES * 128;
    _Float16* h0  = mh + (size_t)N_NODES * 128;
    _Float16* h1  = h0 + (size_t)N_NODES * 128;
    _Float16* Wc0 = h1 + (size_t)N_NODES * 128;
    _Float16* Wc1 = Wc0 + 8 * 8 * 64 * 8;
    _Float16* Wc2 = Wc1 + 8 * 8 * 64 * 8;

    hipMemsetAsync(deg, 0, 50016 * sizeof(int), stream);

    const int edgeBlocks = (N_EDGES + 255) / 256;
    const int scanBlocks = (N_NODES + 1023) / 1024;
    k_deg<<<edgeBlocks, 256, 0, stream>>>(dst, deg, rank);
    k_scan1<<<scanBlocks, 1024, 0, stream>>>(deg, offsets, partials);
    k_scan2<<<1, 64, 0, stream>>>(partials, scanBlocks);
    k_scan3<<<(N_NODES + 255) / 256, 256, 0, stream>>>(offsets, partials);
    k_scatter<<<edgeBlocks, 256, 0, stream>>>(src, dst, offsets, rank, sorted);

    // prep: fp16 features + swizzled fp16 weights
    k_cvt<<<(N_NODES * 128 / 4 + 255) / 256, 256, 0, stream>>>(x, xh, N_NODES * 128 / 4);
    k_cvt_w<<<8 * 8, 64, 0, stream>>>(Wl0, Wr0, HIDDEN, 8, Wc0);
    k_cvt_w<<<8 * 8, 64, 0, stream>>>(Wl1, Wr1, HIDDEN, 8, Wc1);
    k_cvt_w<<<8 * 3, 64, 0, stream>>>(Wl2, Wr2, N_CLASSES, 3, Wc2);

    const int waveBlocks = (N_NODES * 64 + 255) / 256;
    const int gemmBlocks = ((N_NODES + 31) / 32 + 3) / 4;

    // layer 0
    k_agg_h<<<waveBlocks, 256, 0, stream>>>(xh, offsets, deg, sorted, mh);
    k_gemm_h<<<gemmBlocks, 256, 0, stream>>>(mh, xh, Wc0, bl0, h0);
    // layer 1
    k_agg_h<<<waveBlocks, 256, 0, stream>>>(h0, offsets, deg, sorted, mh);
    k_gemm_h<<<gemmBlocks, 256, 0, stream>>>(mh, h0, Wc1, bl1, h1);
    // layer 2 + log_softmax
    k_agg_h<<<waveBlocks, 256, 0, stream>>>(h1, offsets, deg, sorted, mh);
    k_gemm_f<<<gemmBlocks, 256, 0, stream>>>(mh, h1, Wc2, bl2, out);
}

// Round 6
// 309.814 us; speedup vs baseline: 2.6128x; 1.0458x over previous
//
#include <hip/hip_runtime.h>
#include <cstdint>
#include <cstddef>
#include <cmath>

#define N_NODES 50000
#define N_EDGES 800000
#define D_FEAT 128
#define HIDDEN 128
#define N_CLASSES 40

typedef _Float16 half8 __attribute__((ext_vector_type(8)));
typedef _Float16 half4 __attribute__((ext_vector_type(4)));
typedef float f32x4 __attribute__((ext_vector_type(4)));

// ---------------- CSR build ----------------

__global__ __launch_bounds__(256) void k_deg(const int* __restrict__ dst, int* __restrict__ deg,
                                             unsigned short* __restrict__ rank) {
    int e = blockIdx.x * 256 + threadIdx.x;
    if (e < N_EDGES) {
        int r = atomicAdd(&deg[dst[e]], 1);
        rank[e] = (unsigned short)r;
    }
}

__global__ __launch_bounds__(1024) void k_scan1(const int* __restrict__ deg, int* __restrict__ offsets,
                                                int* __restrict__ partials) {
    __shared__ int wsums[16];
    int tid = threadIdx.x;
    int g = blockIdx.x * 1024 + tid;
    int v = (g < N_NODES) ? deg[g] : 0;
    int lane = tid & 63;
    int wid = tid >> 6;
    int incl = v;
    #pragma unroll
    for (int off = 1; off < 64; off <<= 1) {
        int t = __shfl_up(incl, off);
        if (lane >= off) incl += t;
    }
    if (lane == 63) wsums[wid] = incl;
    __syncthreads();
    if (wid == 0) {
        int wv = (lane < 16) ? wsums[lane] : 0;
        int wincl = wv;
        #pragma unroll
        for (int off = 1; off < 16; off <<= 1) {
            int t = __shfl_up(wincl, off);
            if (lane >= off) wincl += t;
        }
        if (lane < 16) wsums[lane] = wincl - wv;
    }
    __syncthreads();
    if (g < N_NODES) offsets[g] = wsums[wid] + incl - v;
    if (tid == 1023) partials[blockIdx.x] = wsums[15] + incl;
}

__global__ __launch_bounds__(64) void k_scan2(int* __restrict__ partials, int nParts) {
    int lane = threadIdx.x;
    int v = (lane < nParts) ? partials[lane] : 0;
    int incl = v;
    #pragma unroll
    for (int off = 1; off < 64; off <<= 1) {
        int t = __shfl_up(incl, off);
        if (lane >= off) incl += t;
    }
    if (lane < nParts) partials[lane] = incl - v;
}

__global__ __launch_bounds__(256) void k_scan3(int* __restrict__ offsets, const int* __restrict__ partials) {
    int g = blockIdx.x * 256 + threadIdx.x;
    if (g < N_NODES) offsets[g] += partials[g >> 10];
}

__global__ __launch_bounds__(256) void k_scatter(const int* __restrict__ src, const int* __restrict__ dst,
                                                 const int* __restrict__ offsets,
                                                 const unsigned short* __restrict__ rank,
                                                 unsigned short* __restrict__ sorted_src) {
    int e = blockIdx.x * 256 + threadIdx.x;
    if (e < N_EDGES) {
        int d = dst[e];
        int pos = offsets[d] + (int)rank[e];
        sorted_src[pos] = (unsigned short)src[e];
    }
}

// ---------------- combined prep: feature fp32->fp16 + weight swizzle ----------------
// blocks [0, 6250): feature convert (float4 granules)
// blocks [6250, 6250+16): Wc0   [+16, +32): Wc1   [+32, +38): Wc2
// W swizzle cell (t, f): k = t*32 + (l>>4)*8 + i, n = f*16 + (l&15); 4 cells per block.

#define CVT_BLOCKS 6250

__global__ __launch_bounds__(256) void k_prep(const float* __restrict__ x, _Float16* __restrict__ xh,
                                              const float* __restrict__ Wl0, const float* __restrict__ Wr0, _Float16* __restrict__ Wc0,
                                              const float* __restrict__ Wl1, const float* __restrict__ Wr1, _Float16* __restrict__ Wc1,
                                              const float* __restrict__ Wl2, const float* __restrict__ Wr2, _Float16* __restrict__ Wc2) {
    int bid = blockIdx.x;
    if (bid < CVT_BLOCKS) {
        int i = bid * 256 + threadIdx.x;
        float4 v = *(const float4*)(x + (size_t)i * 4);
        half4 o;
        o[0] = (_Float16)v.x; o[1] = (_Float16)v.y; o[2] = (_Float16)v.z; o[3] = (_Float16)v.w;
        *(half4*)(xh + (size_t)i * 4) = o;
        return;
    }
    bid -= CVT_BLOCKS;
    const float* Wl; const float* Wr; _Float16* dst; int NF, Nout, cell0;
    if (bid < 16)      { Wl = Wl0; Wr = Wr0; dst = Wc0; NF = 8; Nout = 128; cell0 = bid * 4; }
    else if (bid < 32) { Wl = Wl1; Wr = Wr1; dst = Wc1; NF = 8; Nout = 128; cell0 = (bid - 16) * 4; }
    else               { Wl = Wl2; Wr = Wr2; dst = Wc2; NF = 3; Nout = 40;  cell0 = (bid - 32) * 4; }
    int cell = cell0 + (threadIdx.x >> 6);
    int t = cell / NF;
    int f = cell % NF;
    int l = threadIdx.x & 63;
    int kb = t * 32 + (l >> 4) * 8;
    int n = f * 16 + (l & 15);
    half8 v;
    #pragma unroll
    for (int i = 0; i < 8; ++i) {
        int k = kb + i;
        float w = 0.f;
        if (n < Nout) w = (k < 128) ? Wl[k * Nout + n] : Wr[(k - 128) * Nout + n];
        v[i] = (_Float16)w;
    }
    *(half8*)(dst + ((size_t)cell * 64 + l) * 8) = v;
}

// ---------------- mean aggregation: one wave per node, 4 edge-rows in flight ----------------

__global__ __launch_bounds__(256) void k_agg_h(const _Float16* __restrict__ feat, const int* __restrict__ offsets,
                                               const int* __restrict__ deg,
                                               const unsigned short* __restrict__ sorted_src,
                                               _Float16* __restrict__ mean) {
    int wave = (int)((blockIdx.x * 256 + threadIdx.x) >> 6);
    int lane = threadIdx.x & 63;
    if (wave >= N_NODES) return;
    int start = offsets[wave];
    int cnt = deg[wave];
    int grp = lane >> 4;
    int cl = lane & 15;
    float acc[8] = {0.f, 0.f, 0.f, 0.f, 0.f, 0.f, 0.f, 0.f};
    #pragma unroll 4
    for (int i = 0; i < cnt; i += 4) {
        int e = i + grp;
        if (e < cnt) {
            int s = (int)sorted_src[start + e];
            half8 v = *(const half8*)(feat + (size_t)s * 128 + cl * 8);
            #pragma unroll
            for (int j = 0; j < 8; ++j) acc[j] += (float)v[j];
        }
    }
    #pragma unroll
    for (int j = 0; j < 8; ++j) {
        acc[j] += __shfl_xor(acc[j], 16);
        acc[j] += __shfl_xor(acc[j], 32);
    }
    if (grp == 0) {
        float r = 1.0f / (float)(cnt > 0 ? cnt : 1);
        half8 o;
        #pragma unroll
        for (int j = 0; j < 8; ++j) o[j] = (_Float16)(acc[j] * r);
        *(half8*)(mean + (size_t)wave * 128 + cl * 8) = o;
    }
}

// ---------------- hidden layer MFMA GEMM with LDS-staged A/B tiles ----------------
// block: 256 thr = 4 waves, 128 rows; LDS: sA/sB 128x128 fp16 (32 KB each), chunk^row swizzle
// wave w: rows w*32..w*32+31; per t: a0/a1 from LDS, b from global Wc (coalesced)

__global__ __launch_bounds__(256) void k_gemm_h(const _Float16* __restrict__ A, const _Float16* __restrict__ B,
                                                const _Float16* __restrict__ Wc, const float* __restrict__ bias,
                                                _Float16* __restrict__ outp) {
    __shared__ _Float16 sA[128 * 128];
    __shared__ _Float16 sB[128 * 128];
    int tid = threadIdx.x;
    int rows0 = blockIdx.x * 128;
    for (int i = 0; i < 8; ++i) {
        int cid = i * 256 + tid;        // 0..2047
        int r = cid >> 4;               // tile row
        int ch = cid & 15;              // 16B chunk in row
        int gr = rows0 + r;
        int grc = gr < N_NODES ? gr : N_NODES - 1;
        half8 va = *(const half8*)(A + (size_t)grc * 128 + ch * 8);
        half8 vb = *(const half8*)(B + (size_t)grc * 128 + ch * 8);
        int sch = ch ^ (r & 15);
        *(half8*)(sA + r * 128 + sch * 8) = va;
        *(half8*)(sB + r * 128 + sch * 8) = vb;
    }
    __syncthreads();
    int w = tid >> 6;
    int lane = tid & 63;
    int ln = lane & 15, lg = lane >> 4;
    int r0 = w * 32 + ln;
    int r1 = r0 + 16;
    f32x4 acc[2][8];
    #pragma unroll
    for (int i = 0; i < 2; ++i)
        #pragma unroll
        for (int f = 0; f < 8; ++f) acc[i][f] = (f32x4){0.f, 0.f, 0.f, 0.f};
    #pragma unroll
    for (int t = 0; t < 8; ++t) {
        const _Float16* P = (t < 4) ? sA : sB;
        int ch = (t & 3) * 4 + lg;      // chunk index 0..15 (k-elems [ch*8, ch*8+8))
        half8 a0 = *(const half8*)(P + r0 * 128 + (ch ^ (r0 & 15)) * 8);
        half8 a1 = *(const half8*)(P + r1 * 128 + (ch ^ (r1 & 15)) * 8);
        #pragma unroll
        for (int f = 0; f < 8; ++f) {
            half8 b = *(const half8*)(Wc + ((size_t)(t * 8 + f) * 64 + lane) * 8);
            acc[0][f] = __builtin_amdgcn_mfma_f32_16x16x32_f16(a0, b, acc[0][f], 0, 0, 0);
            acc[1][f] = __builtin_amdgcn_mfma_f32_16x16x32_f16(a1, b, acc[1][f], 0, 0, 0);
        }
    }
    int rw = rows0 + w * 32;
    #pragma unroll
    for (int mf = 0; mf < 2; ++mf) {
        #pragma unroll
        for (int f = 0; f < 8; ++f) {
            int n = f * 16 + ln;
            float bv = bias[n];
            #pragma unroll
            for (int r = 0; r < 4; ++r) {
                int m = rw + mf * 16 + lg * 4 + r;
                if (m < N_NODES) {
                    float v = fmaxf(acc[mf][f][r] + bv, 0.f);
                    outp[(size_t)m * 128 + n] = (_Float16)v;
                }
            }
        }
    }
}

// ---------------- final layer MFMA GEMM (N=40 pad 48) + relu + log_softmax, LDS-staged ----------------

__global__ __launch_bounds__(256) void k_gemm_f(const _Float16* __restrict__ A, const _Float16* __restrict__ B,
                                                const _Float16* __restrict__ Wc, const float* __restrict__ bias,
                                                float* __restrict__ outp) {
    __shared__ _Float16 sA[128 * 128];
    __shared__ _Float16 sB[128 * 128];
    int tid = threadIdx.x;
    int rows0 = blockIdx.x * 128;
    for (int i = 0; i < 8; ++i) {
        int cid = i * 256 + tid;
        int r = cid >> 4;
        int ch = cid & 15;
        int gr = rows0 + r;
        int grc = gr < N_NODES ? gr : N_NODES - 1;
        half8 va = *(const half8*)(A + (size_t)grc * 128 + ch * 8);
        half8 vb = *(const half8*)(B + (size_t)grc * 128 + ch * 8);
        int sch = ch ^ (r & 15);
        *(half8*)(sA + r * 128 + sch * 8) = va;
        *(half8*)(sB + r * 128 + sch * 8) = vb;
    }
    __syncthreads();
    int w = tid >> 6;
    int lane = tid & 63;
    int ln = lane & 15, lg = lane >> 4;
    int r0 = w * 32 + ln;
    int r1 = r0 + 16;
    f32x4 acc[2][3];
    #pragma unroll
    for (int i = 0; i < 2; ++i)
        #pragma unroll
        for (int f = 0; f < 3; ++f) acc[i][f] = (f32x4){0.f, 0.f, 0.f, 0.f};
    #pragma unroll
    for (int t = 0; t < 8; ++t) {
        const _Float16* P = (t < 4) ? sA : sB;
        int ch = (t & 3) * 4 + lg;
        half8 a0 = *(const half8*)(P + r0 * 128 + (ch ^ (r0 & 15)) * 8);
        half8 a1 = *(const half8*)(P + r1 * 128 + (ch ^ (r1 & 15)) * 8);
        #pragma unroll
        for (int f = 0; f < 3; ++f) {
            half8 b = *(const half8*)(Wc + ((size_t)(t * 3 + f) * 64 + lane) * 8);
            acc[0][f] = __builtin_amdgcn_mfma_f32_16x16x32_f16(a0, b, acc[0][f], 0, 0, 0);
            acc[1][f] = __builtin_amdgcn_mfma_f32_16x16x32_f16(a1, b, acc[1][f], 0, 0, 0);
        }
    }
    float bv[3];
    #pragma unroll
    for (int f = 0; f < 3; ++f) {
        int n = f * 16 + ln;
        bv[f] = (n < N_CLASSES) ? bias[n] : 0.f;
    }
    int rw = rows0 + w * 32;
    #pragma unroll
    for (int mf = 0; mf < 2; ++mf) {
        #pragma unroll
        for (int r = 0; r < 4; ++r) {
            int m = rw + mf * 16 + lg * 4 + r;
            float v[3];
            float vmax = -INFINITY;
            #pragma unroll
            for (int f = 0; f < 3; ++f) {
                int n = f * 16 + ln;
                v[f] = fmaxf(acc[mf][f][r] + bv[f], 0.f);
                if (n < N_CLASSES) vmax = fmaxf(vmax, v[f]);
            }
            #pragma unroll
            for (int off = 1; off < 16; off <<= 1) vmax = fmaxf(vmax, __shfl_xor(vmax, off));
            float s = 0.f;
            #pragma unroll
            for (int f = 0; f < 3; ++f) {
                int n = f * 16 + ln;
                if (n < N_CLASSES) s += expf(v[f] - vmax);
            }
            #pragma unroll
            for (int off = 1; off < 16; off <<= 1) s += __shfl_xor(s, off);
            float lse = vmax + logf(s);
            if (m < N_NODES) {
                #pragma unroll
                for (int f = 0; f < 3; ++f) {
                    int n = f * 16 + ln;
                    if (n < N_CLASSES) outp[(size_t)m * N_CLASSES + n] = v[f] - lse;
                }
            }
        }
    }
}

extern "C" void kernel_launch(void* const* d_in, const int* in_sizes, int n_in,
                              void* d_out, int out_size, void* d_ws, size_t ws_size,
                              hipStream_t stream) {
    const float* x   = (const float*)d_in[0];
    const int*   ei  = (const int*)d_in[1];
    const float* Wl0 = (const float*)d_in[2];
    const float* bl0 = (const float*)d_in[3];
    const float* Wr0 = (const float*)d_in[4];
    const float* Wl1 = (const float*)d_in[5];
    const float* bl1 = (const float*)d_in[6];
    const float* Wr1 = (const float*)d_in[7];
    const float* Wl2 = (const float*)d_in[8];
    const float* bl2 = (const float*)d_in[9];
    const float* Wr2 = (const float*)d_in[10];
    float* out = (float*)d_out;

    const int* src = ei;
    const int* dst = ei + N_EDGES;

    // workspace layout
    int* offsets  = (int*)d_ws;                                  // 50016 ints
    int* deg      = offsets + 50016;                             // 50016 ints
    int* partials = deg + 50016;                                 // 64 ints
    unsigned short* rank   = (unsigned short*)(partials + 64);   // 800k u16
    unsigned short* sorted = rank + N_EDGES;                     // 800k u16
    _Float16* xh  = (_Float16*)(sorted + N_EDGES);
    _Float16* mh  = xh + (size_t)N_NODES * 128;
    _Float16* h0  = mh + (size_t)N_NODES * 128;
    _Float16* h1  = h0 + (size_t)N_NODES * 128;
    _Float16* Wc0 = h1 + (size_t)N_NODES * 128;
    _Float16* Wc1 = Wc0 + 8 * 8 * 64 * 8;
    _Float16* Wc2 = Wc1 + 8 * 8 * 64 * 8;

    hipMemsetAsync(deg, 0, 50016 * sizeof(int), stream);

    const int edgeBlocks = (N_EDGES + 255) / 256;
    const int scanBlocks = (N_NODES + 1023) / 1024;
    k_deg<<<edgeBlocks, 256, 0, stream>>>(dst, deg, rank);
    k_scan1<<<scanBlocks, 1024, 0, stream>>>(deg, offsets, partials);
    k_scan2<<<1, 64, 0, stream>>>(partials, scanBlocks);
    k_scan3<<<(N_NODES + 255) / 256, 256, 0, stream>>>(offsets, partials);
    k_scatter<<<edgeBlocks, 256, 0, stream>>>(src, dst, offsets, rank, sorted);

    k_prep<<<CVT_BLOCKS + 38, 256, 0, stream>>>(x, xh, Wl0, Wr0, Wc0, Wl1, Wr1, Wc1, Wl2, Wr2, Wc2);

    const int waveBlocks = (N_NODES * 64 + 255) / 256;
    const int gemmBlocks = (N_NODES + 127) / 128;

    // layer 0
    k_agg_h<<<waveBlocks, 256, 0, stream>>>(xh, offsets, deg, sorted, mh);
    k_gemm_h<<<gemmBlocks, 256, 0, stream>>>(mh, xh, Wc0, bl0, h0);
    // layer 1
    k_agg_h<<<waveBlocks, 256, 0, stream>>>(h0, offsets, deg, sorted, mh);
    k_gemm_h<<<gemmBlocks, 256, 0, stream>>>(mh, h0, Wc1, bl1, h1);
    // layer 2 + log_softmax
    k_agg_h<<<waveBlocks, 256, 0, stream>>>(h1, offsets, deg, sorted, mh);
    k_gemm_f<<<gemmBlocks, 256, 0, stream>>>(mh, h1, Wc2, bl2, out);
}